// Round 2
// baseline (290.360 us; speedup 1.0000x reference)
//
#include <hip/hip_runtime.h>
#include <math.h>

// ExpertGate — np.einsum-bitwise-replication version.
//
// The harness compares indices against a numpy reference (ref=np) with a
// threshold that demands exact top-8 index match. Near-tie analysis of rounds
// 0/1 shows ANY accumulation order that isn't bitwise-identical to the np ref
// flips ~1 token's indices. So this kernel replicates numpy's einsum float32
// sum_of_products_contig_two (numpy >=1.20, SSE3 baseline, no FMA) EXACTLY:
//
//   - 4 interleaved accumulator chains (k mod 4), one SSE lane each
//   - k consumed in groups of 16; within a group the four quads are
//     accumulated in REVERSE order (j = 3,2,1,0):
//       ab3 = a3*b3 + acc; ab2 = a2*b2 + ab3; ab1 = a1*b1 + ab2; acc = a0*b0 + ab1
//   - separate mul and add roundings (__fmul_rn/__fadd_rn — no contraction)
//   - final reduce: (c0+c1) + (c2+c3)   (npyv_sum_f32 = 2x hadd on SSE3)
//   - 2048 % 16 == 0 -> no tail loop
//
// Sigmoid mimics np: e = float(exp(-(double)z)) [~correctly-rounded fp32 exp],
// s = 1/(1+e) in fp32. Ties at fp32-sigmoid level break by LOWER index
// (= stable argsort = lax.top_k).
//
// Consequence: NO split-K (order matters). Each thread walks all 2048 k for
// its 2 tokens x 4 experts, keeping 32 fp32 chain accumulators.

#define D_DIM 2048
#define E_DIM 64
#define TOPK 8
#define TM 32        // tokens per block
#define BK 64        // k-chunk staged per round (4 groups of 16)
#define XS 68        // Xs row stride (floats): 16B-aligned, non-pow2
#define WS 68
#define SCS 65

__global__ __launch_bounds__(256) void expert_gate_kernel(
    const float* __restrict__ x,      // (N, 2048)
    const float* __restrict__ w,      // (64, 2048)
    const float* __restrict__ bias,   // (64,)
    float* __restrict__ out,          // N*8 weights, then N*8 indices-as-float
    int N)
{
    __shared__ float Xs[TM * XS];
    __shared__ float Ws[E_DIM * WS];
    __shared__ float Sc[TM * SCS];

    const int t    = threadIdx.x;
    const int tx   = t & 15;   // experts tx + 16*e, e=0..3
    const int ty   = t >> 4;   // tokens  ty + 16*i, i=0..1
    const int tok0 = blockIdx.x * TM;
    const int lane = t & 63;
    const float my_bias = bias[lane];

    // c[token][expert][chain l], chain l accumulates k % 4 == l
    float c[2][4][4];
    #pragma unroll
    for (int i = 0; i < 2; ++i)
        #pragma unroll
        for (int e = 0; e < 4; ++e)
            #pragma unroll
            for (int l = 0; l < 4; ++l) c[i][e][l] = 0.f;

    for (int k0 = 0; k0 < D_DIM; k0 += BK) {
        // ---- stage X tile: 32 rows x 64 floats (512 float4, 2/thread) ----
        {
            int f = t;
            int row = f >> 4, col = (f & 15) << 2;
            float4 v = *reinterpret_cast<const float4*>(
                &x[(size_t)(tok0 + row) * D_DIM + k0 + col]);
            *reinterpret_cast<float4*>(&Xs[row * XS + col]) = v;
            f = t + 256;
            row = f >> 4; col = (f & 15) << 2;
            v = *reinterpret_cast<const float4*>(
                &x[(size_t)(tok0 + row) * D_DIM + k0 + col]);
            *reinterpret_cast<float4*>(&Xs[row * XS + col]) = v;
        }
        // ---- stage W tile: 64 rows x 64 floats (1024 float4, 4/thread) ----
        #pragma unroll
        for (int i = 0; i < 4; ++i) {
            int f = t + i * 256;
            int row = f >> 4, col = (f & 15) << 2;
            float4 v = *reinterpret_cast<const float4*>(
                &w[(size_t)row * D_DIM + k0 + col]);
            *reinterpret_cast<float4*>(&Ws[row * WS + col]) = v;
        }
        __syncthreads();

        // ---- accumulate: 4 groups of 16 k, quads within group in order 3,2,1,0 ----
        #pragma unroll
        for (int g = 0; g < 4; ++g) {
            float4 xa[2][4];   // [token i][quad j]
            #pragma unroll
            for (int i = 0; i < 2; ++i)
                #pragma unroll
                for (int j = 0; j < 4; ++j)
                    xa[i][j] = *reinterpret_cast<const float4*>(
                        &Xs[(ty + 16 * i) * XS + g * 16 + 4 * j]);
            float4 wb[4][4];   // [expert e][quad j]
            #pragma unroll
            for (int e = 0; e < 4; ++e)
                #pragma unroll
                for (int j = 0; j < 4; ++j)
                    wb[e][j] = *reinterpret_cast<const float4*>(
                        &Ws[(tx + 16 * e) * WS + g * 16 + 4 * j]);

            #pragma unroll
            for (int j = 3; j >= 0; --j) {
                #pragma unroll
                for (int i = 0; i < 2; ++i) {
                    #pragma unroll
                    for (int e = 0; e < 4; ++e) {
                        c[i][e][0] = __fadd_rn(c[i][e][0], __fmul_rn(xa[i][j].x, wb[e][j].x));
                        c[i][e][1] = __fadd_rn(c[i][e][1], __fmul_rn(xa[i][j].y, wb[e][j].y));
                        c[i][e][2] = __fadd_rn(c[i][e][2], __fmul_rn(xa[i][j].z, wb[e][j].z));
                        c[i][e][3] = __fadd_rn(c[i][e][3], __fmul_rn(xa[i][j].w, wb[e][j].w));
                    }
                }
            }
        }
        __syncthreads();
    }

    // ---- finalize: (c0+c1)+(c2+c3), fp32 sigmoid exactly like np ----
    #pragma unroll
    for (int i = 0; i < 2; ++i) {
        #pragma unroll
        for (int e = 0; e < 4; ++e) {
            float z = __fadd_rn(__fadd_rn(c[i][e][0], c[i][e][1]),
                                __fadd_rn(c[i][e][2], c[i][e][3]));
            // np: 1.0/(1.0 + np.exp(-z)) in float32; our exp is the correctly-
            // rounded fp32 value via double exp.
            float ez = (float)exp(-(double)z);
            float s  = __fdiv_rn(1.0f, __fadd_rn(1.0f, ez));
            Sc[(ty + 16 * i) * SCS + (tx + 16 * e)] = s;
        }
    }
    __syncthreads();

    // ---- top-8 per token: lane == expert; each wave handles 8 tokens ----
    const int wave = t >> 6;  // 0..3
    for (int r = 0; r < 8; ++r) {
        const int tok = wave * 8 + r;
        const float s = Sc[tok * SCS + lane];  // original fp32 score
        float rv = __fadd_rn(s, my_bias);      // routing score (bias is 0.0f)
        float outw = 0.f;
        int   outi = 0;
        float ssum = 0.f;
        #pragma unroll
        for (int sel = 0; sel < TOPK; ++sel) {
            float v = rv;
            int   vi = lane;
            // 64-lane butterfly lexicographic max (ties -> lower index, = top_k)
            #pragma unroll
            for (int off = 1; off < 64; off <<= 1) {
                float ov = __shfl_xor(v, off);
                int   oi = __shfl_xor(vi, off);
                if (ov > v || (ov == v && oi < vi)) { v = ov; vi = oi; }
            }
            float cs = __shfl(s, vi);  // un-biased score of winner
            ssum = __fadd_rn(ssum, cs);
            if (lane == sel) { outw = cs; outi = vi; }
            if (lane == vi) rv = -INFINITY;
        }
        if (lane < TOPK) {
            const size_t base = (size_t)(tok0 + tok) * TOPK + lane;
            out[base] = __fmul_rn(__fdiv_rn(outw, __fadd_rn(ssum, 1e-8f)), 2.5f);
            out[(size_t)N * TOPK + base] = (float)outi;
        }
    }
}

extern "C" void kernel_launch(void* const* d_in, const int* in_sizes, int n_in,
                              void* d_out, int out_size, void* d_ws, size_t ws_size,
                              hipStream_t stream) {
    const float* x    = (const float*)d_in[0];
    const float* w    = (const float*)d_in[1];
    const float* bias = (const float*)d_in[2];
    float* out = (float*)d_out;
    const int N = in_sizes[0] / D_DIM;  // 16384
    const int grid = N / TM;            // 512
    expert_gate_kernel<<<grid, 256, 0, stream>>>(x, w, bias, out, N);
}